// Round 7
// baseline (279.681 us; speedup 1.0000x reference)
//
#include <hip/hip_runtime.h>
#include <math.h>

// Problem constants
#define BATCH 4
#define SEQ   4096
#define DIM   2048
#define DS    64
#define NF    4096
#define NR    2048
#define NT    2048
#define NTOT  8192          // NF+NR+NT
#define TOK   16384         // BATCH*SEQ
#define KSPLIT 4

typedef __attribute__((ext_vector_type(8))) __bf16 bf16x8;
typedef __attribute__((ext_vector_type(4))) float  f32x4;

static __device__ __forceinline__ unsigned short f2bf(float x) {
  unsigned int u = __float_as_uint(x);
  u += 0x7fffu + ((u >> 16) & 1u);       // round-to-nearest-even
  return (unsigned short)(u >> 16);
}
static __device__ __forceinline__ float bf2f(unsigned int lo16) {
  return __uint_as_float(lo16 << 16);
}

// ---------------------------------------------------------------------------
// P0: normalized emb -> split bf16 (hi, lo), scale pre-applied.
// ---------------------------------------------------------------------------
__global__ __launch_bounds__(256) void k_prep_emb(const float* __restrict__ emb,
                                                  unsigned short* __restrict__ eh,
                                                  unsigned short* __restrict__ el) {
  int row  = blockIdx.x * 4 + (threadIdx.x >> 6);
  int lane = threadIdx.x & 63;
  float v  = emb[(size_t)row * DS + lane];
  float ss = v * v;
#pragma unroll
  for (int m = 32; m >= 1; m >>= 1) ss += __shfl_xor(ss, m, 64);
  float sc = 1.0f / fmaxf(sqrtf(ss), 1e-12f);
  float w  = v * sc;
  unsigned short hi = f2bf(w);
  eh[(size_t)row * DS + lane] = hi;
  el[(size_t)row * DS + lane] = f2bf(w - bf2f(hi));
}

// ---------------------------------------------------------------------------
// P1: W [2048][64] -> transposed split bf16 wt[c][k] (hi, lo)
// ---------------------------------------------------------------------------
__global__ __launch_bounds__(256) void k_prep_w(const float* __restrict__ W,
                                                unsigned short* __restrict__ wth,
                                                unsigned short* __restrict__ wtl) {
  int c = blockIdx.x;
#pragma unroll
  for (int it = 0; it < 8; ++it) {
    int k = threadIdx.x + it * 256;
    float v = W[(size_t)k * DS + c];
    unsigned short hi = f2bf(v);
    wth[(size_t)c * DIM + k] = hi;
    wtl[(size_t)c * DIM + k] = f2bf(v - bf2f(hi));
  }
}

// ---------------------------------------------------------------------------
// K1: h-partials = x @ W  (K-split 4, f32 partial out).
// grid (TOK/64, 4), 256 thr (4 waves), tile 64 tok x 64 col, K-step 32,
// double-buffered LDS + 2-deep register prefetch. 32 KB LDS -> 4 blk/CU.
// ---------------------------------------------------------------------------
__global__ __launch_bounds__(256) void k_h(
    const float* __restrict__ x, const unsigned short* __restrict__ wth,
    const unsigned short* __restrict__ wtl, float* __restrict__ Hpart) {
  __shared__ __align__(16) unsigned short xh[2][64 * 32];   // 4 KB each
  __shared__ __align__(16) unsigned short xl[2][64 * 32];
  __shared__ __align__(16) unsigned short wh[2][64 * 32];
  __shared__ __align__(16) unsigned short wl[2][64 * 32];   // 32 KB total
  const int tid  = threadIdx.x;
  const int t0   = blockIdx.x * 64;
  const int kbase = blockIdx.y * (DIM / KSPLIT);            // 512
  const int lane = tid & 63, wv = tid >> 6;
  const int fr   = lane & 15, oct = lane >> 4;

  float4 xrA[2], xrB[2];
  uint4  wrA[2], wrB[2];   // [0]=hi [1]=lo

  auto LOADX = [&](int k0, float4* xr, uint4* wr) {
#pragma unroll
    for (int it = 0; it < 2; ++it) {
      int idx = tid + it * 256;
      int r = idx >> 3, q = idx & 7;
      xr[it] = *reinterpret_cast<const float4*>(
          &x[(size_t)(t0 + r) * DIM + k0 + q * 4]);
    }
    int c = tid >> 2, s = tid & 3;
    size_t bo = ((size_t)c * DIM + k0 + s * 8) * 2;
    wr[0] = *reinterpret_cast<const uint4*>((const char*)wth + bo);
    wr[1] = *reinterpret_cast<const uint4*>((const char*)wtl + bo);
  };
  auto STORE = [&](int buf, float4* xr, uint4* wr) {
#pragma unroll
    for (int it = 0; it < 2; ++it) {
      int idx = tid + it * 256;
      int r = idx >> 3, q = idx & 7;
      int bo = (r * 64 + q * 8) ^ ((r & 3) << 4);
      float4 v = xr[it];
      unsigned short a0 = f2bf(v.x), a1 = f2bf(v.y), a2 = f2bf(v.z), a3 = f2bf(v.w);
      uint2 hi; hi.x = a0 | ((unsigned)a1 << 16); hi.y = a2 | ((unsigned)a3 << 16);
      *reinterpret_cast<uint2*>((char*)xh[buf] + bo) = hi;
      uint2 lo;
      lo.x = (unsigned)f2bf(v.x - bf2f(a0)) | ((unsigned)f2bf(v.y - bf2f(a1)) << 16);
      lo.y = (unsigned)f2bf(v.z - bf2f(a2)) | ((unsigned)f2bf(v.w - bf2f(a3)) << 16);
      *reinterpret_cast<uint2*>((char*)xl[buf] + bo) = lo;
    }
    int c = tid >> 2, s = tid & 3;
    int bo = (c * 64 + s * 16) ^ ((c & 3) << 4);
    *reinterpret_cast<uint4*>((char*)wh[buf] + bo) = wr[0];
    *reinterpret_cast<uint4*>((char*)wl[buf] + bo) = wr[1];
  };

  f32x4 acc[4];
#pragma unroll
  for (int j = 0; j < 4; ++j) acc[j] = (f32x4)0.0f;

  auto COMPUTE = [&](int buf) {
    int row = wv * 16 + fr;
    int boA = (row * 64 + oct * 16) ^ ((row & 3) << 4);
    bf16x8 ah  = *reinterpret_cast<const bf16x8*>((const char*)xh[buf] + boA);
    bf16x8 al_ = *reinterpret_cast<const bf16x8*>((const char*)xl[buf] + boA);
#pragma unroll
    for (int j = 0; j < 4; ++j) {
      int c = j * 16 + fr;
      int boB = (c * 64 + oct * 16) ^ ((c & 3) << 4);
      bf16x8 bh  = *reinterpret_cast<const bf16x8*>((const char*)wh[buf] + boB);
      bf16x8 bl_ = *reinterpret_cast<const bf16x8*>((const char*)wl[buf] + boB);
      acc[j] = __builtin_amdgcn_mfma_f32_16x16x32_bf16(ah,  bh,  acc[j], 0, 0, 0);
      acc[j] = __builtin_amdgcn_mfma_f32_16x16x32_bf16(ah,  bl_, acc[j], 0, 0, 0);
      acc[j] = __builtin_amdgcn_mfma_f32_16x16x32_bf16(al_, bh,  acc[j], 0, 0, 0);
    }
  };

  LOADX(kbase, xrA, wrA);
  LOADX(kbase + 32, xrB, wrB);
  for (int s = 0; s < 16; s += 2) {
    STORE(0, xrA, wrA);
    if (s + 2 < 16) LOADX(kbase + (s + 2) * 32, xrA, wrA);
    __syncthreads();
    COMPUTE(0);
    STORE(1, xrB, wrB);
    if (s + 3 < 16) LOADX(kbase + (s + 3) * 32, xrB, wrB);
    __syncthreads();
    COMPUTE(1);
  }

  // C layout: col = lane&15, row = oct*4 + reg [m89]
  float* op = Hpart + (size_t)blockIdx.y * TOK * DS;
#pragma unroll
  for (int j = 0; j < 4; ++j) {
    int c = j * 16 + fr;
#pragma unroll
    for (int r = 0; r < 4; ++r) {
      int t = t0 + wv * 16 + oct * 4 + r;
      op[(size_t)t * DS + c] = acc[j][r];
    }
  }
}

// ---------------------------------------------------------------------------
// K1b: combine 4 K-split partials + bias -> split bf16 h.
// ---------------------------------------------------------------------------
__global__ __launch_bounds__(256) void k_hc(const float* __restrict__ Hpart,
                                            const float* __restrict__ bias,
                                            unsigned short* __restrict__ hh,
                                            unsigned short* __restrict__ hl) {
  int idx = blockIdx.x * 256 + threadIdx.x;   // 0..TOK*16-1
  int t = idx >> 4, q = idx & 15;
  size_t o = (size_t)t * DS + q * 4;
  float4 s0 = *reinterpret_cast<const float4*>(&Hpart[o]);
  float4 s1 = *reinterpret_cast<const float4*>(&Hpart[(size_t)TOK * DS + o]);
  float4 s2 = *reinterpret_cast<const float4*>(&Hpart[2 * (size_t)TOK * DS + o]);
  float4 s3 = *reinterpret_cast<const float4*>(&Hpart[3 * (size_t)TOK * DS + o]);
  float4 bv = *reinterpret_cast<const float4*>(&bias[q * 4]);
  float v0 = (s0.x + s1.x) + (s2.x + s3.x) + bv.x;
  float v1 = (s0.y + s1.y) + (s2.y + s3.y) + bv.y;
  float v2 = (s0.z + s1.z) + (s2.z + s3.z) + bv.z;
  float v3 = (s0.w + s1.w) + (s2.w + s3.w) + bv.w;
  unsigned short h0 = f2bf(v0), h1 = f2bf(v1), h2 = f2bf(v2), h3 = f2bf(v3);
  uint2 hi; hi.x = h0 | ((unsigned)h1 << 16); hi.y = h2 | ((unsigned)h3 << 16);
  uint2 lo;
  lo.x = (unsigned)f2bf(v0 - bf2f(h0)) | ((unsigned)f2bf(v1 - bf2f(h1)) << 16);
  lo.y = (unsigned)f2bf(v2 - bf2f(h2)) | ((unsigned)f2bf(v3 - bf2f(h3)) << 16);
  *reinterpret_cast<uint2*>(&hh[o]) = hi;
  *reinterpret_cast<uint2*>(&hl[o]) = lo;
}

// ---------------------------------------------------------------------------
// K2: logits GEMM via split-bf16 MFMA, fused epilogues.
// block: 128 tok x 512 neurons (4 subtiles of 128), 256 thr (4 waves).
// T14 async-stage: prefetch next e-subtile to regs before compute.
// MODE 0: Zp[t*16+cb] = sum_n exp(logit)
// MODE 2: Bp[tb*NTOT+n] = sum_t a[sl][t] * exp(logit)
// ---------------------------------------------------------------------------
template<int MODE>
__global__ __launch_bounds__(256) void k_zle(
    const unsigned short* __restrict__ hh, const unsigned short* __restrict__ hl,
    const unsigned short* __restrict__ eh, const unsigned short* __restrict__ el,
    const float* __restrict__ a, float* __restrict__ Zp, float* __restrict__ Bp) {
  __shared__ __align__(16) unsigned short hsh[128 * 64];   // 16 KB each
  __shared__ __align__(16) unsigned short hsl[128 * 64];
  __shared__ __align__(16) unsigned short esh[128 * 64];
  __shared__ __align__(16) unsigned short esl[128 * 64];
  __shared__ float red2[512];                              // MODE2 reduce
  const int tid = threadIdx.x;
  const int tb  = blockIdx.x;          // token block 0..127
  const int cb  = blockIdx.y;          // 512-neuron block 0..15
  const int t0  = tb * 128;

  uint4 erh[4], erl[4];
  auto LOADE = [&](int sub) {
    int n0 = cb * 512 + sub * 128;
#pragma unroll
    for (int it = 0; it < 4; ++it) {
      int idx = tid + it * 256;
      int r = idx >> 3, k8 = idx & 7;
      erh[it] = *reinterpret_cast<const uint4*>(
          (const char*)eh + (size_t)(n0 + r) * 128 + k8 * 16);
      erl[it] = *reinterpret_cast<const uint4*>(
          (const char*)el + (size_t)(n0 + r) * 128 + k8 * 16);
    }
  };
  auto WRITEE = [&]() {
#pragma unroll
    for (int it = 0; it < 4; ++it) {
      int idx = tid + it * 256;
      int r = idx >> 3, k8 = idx & 7;
      int bo = (r * 128 + k8 * 16) ^ ((r & 7) << 4);
      *reinterpret_cast<uint4*>((char*)esh + bo) = erh[it];
      *reinterpret_cast<uint4*>((char*)esl + bo) = erl[it];
    }
  };

  // ---- stage h tile (pure copies) + prefetch e sub0 ----
#pragma unroll
  for (int it = 0; it < 4; ++it) {
    int idx = tid + it * 256;
    int r = idx >> 3, k8 = idx & 7;
    int bo = (r * 128 + k8 * 16) ^ ((r & 7) << 4);
    *reinterpret_cast<uint4*>((char*)hsh + bo) =
        *reinterpret_cast<const uint4*>((const char*)hh + (size_t)(t0 + r) * 128 + k8 * 16);
    *reinterpret_cast<uint4*>((char*)hsl + bo) =
        *reinterpret_cast<const uint4*>((const char*)hl + (size_t)(t0 + r) * 128 + k8 * 16);
  }
  LOADE(0);
  __syncthreads();

  const int lane = tid & 63;
  const int wv   = tid >> 6;
  const int fr   = lane & 15;
  const int oct  = lane >> 4;

  bf16x8 ah[2][2], al[2][2];
#pragma unroll
  for (int i = 0; i < 2; ++i)
#pragma unroll
    for (int kh = 0; kh < 2; ++kh) {
      int row = wv * 32 + i * 16 + fr;
      int bo = (row * 128 + (kh * 32 + oct * 8) * 2) ^ ((row & 7) << 4);
      ah[i][kh] = *reinterpret_cast<const bf16x8*>((const char*)hsh + bo);
      al[i][kh] = *reinterpret_cast<const bf16x8*>((const char*)hsl + bo);
    }
  WRITEE();
  __syncthreads();

  float av[2][4];
  if (MODE == 2) {
    const int sl = (cb < 8) ? 0 : ((cb < 12) ? 1 : 2);
#pragma unroll
    for (int i = 0; i < 2; ++i)
#pragma unroll
      for (int r = 0; r < 4; ++r)
        av[i][r] = a[(size_t)sl * TOK + t0 + wv * 32 + i * 16 + oct * 4 + r];
  }
  float rs[2][4];
#pragma unroll
  for (int i = 0; i < 2; ++i)
#pragma unroll
    for (int r = 0; r < 4; ++r) rs[i][r] = 0.0f;

#pragma unroll
  for (int sub = 0; sub < 4; ++sub) {
    if (sub < 3) LOADE(sub + 1);

    f32x4 acc[2][8];
#pragma unroll
    for (int i = 0; i < 2; ++i)
#pragma unroll
      for (int j = 0; j < 8; ++j) acc[i][j] = (f32x4)0.0f;

#pragma unroll
    for (int j = 0; j < 8; ++j) {
      int col = j * 16 + fr;
      bf16x8 bh[2], bl[2];
#pragma unroll
      for (int kh = 0; kh < 2; ++kh) {
        int bo = (col * 128 + (kh * 32 + oct * 8) * 2) ^ ((col & 7) << 4);
        bh[kh] = *reinterpret_cast<const bf16x8*>((const char*)esh + bo);
        bl[kh] = *reinterpret_cast<const bf16x8*>((const char*)esl + bo);
      }
#pragma unroll
      for (int i = 0; i < 2; ++i) {
#pragma unroll
        for (int kh = 0; kh < 2; ++kh) {
          acc[i][j] = __builtin_amdgcn_mfma_f32_16x16x32_bf16(ah[i][kh], bh[kh], acc[i][j], 0, 0, 0);
          acc[i][j] = __builtin_amdgcn_mfma_f32_16x16x32_bf16(ah[i][kh], bl[kh], acc[i][j], 0, 0, 0);
          acc[i][j] = __builtin_amdgcn_mfma_f32_16x16x32_bf16(al[i][kh], bh[kh], acc[i][j], 0, 0, 0);
        }
      }
    }
    // C/D layout: col = lane&15, row = oct*4 + reg [m89]

    if (MODE == 0) {
#pragma unroll
      for (int i = 0; i < 2; ++i)
#pragma unroll
        for (int j = 0; j < 8; ++j)
#pragma unroll
          for (int r = 0; r < 4; ++r) rs[i][r] += __expf(acc[i][j][r]);
      __syncthreads();                 // esh reads done
      if (sub < 3) { WRITEE(); __syncthreads(); }
    } else {
      float cs[8];
#pragma unroll
      for (int j = 0; j < 8; ++j) {
        float s = 0.0f;
#pragma unroll
        for (int i = 0; i < 2; ++i)
#pragma unroll
          for (int r = 0; r < 4; ++r) s = fmaf(av[i][r], __expf(acc[i][j][r]), s);
        cs[j] = s;
      }
#pragma unroll
      for (int j = 0; j < 8; ++j) {
        cs[j] += __shfl_xor(cs[j], 16, 64);
        cs[j] += __shfl_xor(cs[j], 32, 64);
      }
      if (oct == 0) {
#pragma unroll
        for (int j = 0; j < 8; ++j) red2[wv * 128 + j * 16 + fr] = cs[j];
      }
      __syncthreads();                 // esh reads + red2 writes done
      if (tid < 128) {
        float v = red2[tid] + red2[128 + tid] + red2[256 + tid] + red2[384 + tid];
        Bp[(size_t)tb * NTOT + cb * 512 + sub * 128 + tid] = v;
      }
      if (sub < 3) WRITEE();           // safe: all esh reads done
      __syncthreads();                 // red2 reads + esh writes done
    }
  }

  if (MODE == 0) {
#pragma unroll
    for (int m = 1; m < 16; m <<= 1)
#pragma unroll
      for (int i = 0; i < 2; ++i)
#pragma unroll
        for (int r = 0; r < 4; ++r) rs[i][r] += __shfl_xor(rs[i][r], m, 64);
    if (fr == 0) {
#pragma unroll
      for (int i = 0; i < 2; ++i)
#pragma unroll
        for (int r = 0; r < 4; ++r) {
          int t = t0 + wv * 32 + i * 16 + oct * 4 + r;
          Zp[(size_t)t * 16 + cb] = rs[i][r];
        }
    }
  }
}

// ---------------------------------------------------------------------------
// K3: combine 16 Zp partials per token into a[slice][t] = imp_t / Z_slice
// ---------------------------------------------------------------------------
__global__ __launch_bounds__(256) void k_a2(const float* __restrict__ Zp,
                                            const float* __restrict__ imp,
                                            float* __restrict__ a) {
  int t = blockIdx.x * 256 + threadIdx.x;
  const float4* zp = reinterpret_cast<const float4*>(&Zp[(size_t)t * 16]);
  float4 q0 = zp[0], q1 = zp[1], q2 = zp[2], q3 = zp[3];
  float zf = ((q0.x + q0.y) + (q0.z + q0.w)) + ((q1.x + q1.y) + (q1.z + q1.w));
  float zr = (q2.x + q2.y) + (q2.z + q2.w);
  float zt = (q3.x + q3.y) + (q3.z + q3.w);
  float im = imp[t];
  a[t]           = im / zf;
  a[TOK + t]     = im / zr;
  a[2 * TOK + t] = im / zt;
}

// ---------------------------------------------------------------------------
// K4: reduce the 32 token-block partials -> pooled[b][n].
// ---------------------------------------------------------------------------
__global__ __launch_bounds__(256) void k_red(const float* __restrict__ Bp,
                                             float* __restrict__ pooled) {
  int idx = blockIdx.x * 256 + threadIdx.x;   // 0 .. BATCH*NTOT-1
  int b = idx >> 13;                          // /NTOT
  int n = idx & (NTOT - 1);
  const float* src = Bp + (size_t)(b * 32) * NTOT + n;
  float s = 0.0f;
#pragma unroll
  for (int g = 0; g < 32; ++g) s += src[(size_t)g * NTOT];
  pooled[idx] = s;
}

// ---------------------------------------------------------------------------
// K5: per (batch, slice): top-k over pooled, renorm, scatter.
// ---------------------------------------------------------------------------
__global__ __launch_bounds__(256) void k_topk(const float* __restrict__ pooled,
                                              float* __restrict__ out) {
  __shared__ float p[4096];
  __shared__ float rv[256];
  __shared__ int   ri[256];
  __shared__ float vals[8];
  __shared__ int   idxs[8];
  __shared__ float s_inv;

  const int bid = blockIdx.x;
  const int b   = bid / 3;
  const int sl  = bid % 3;
  const int off = (sl == 0) ? 0 : ((sl == 1) ? NF : NF + NR);
  const int N   = (sl == 0) ? NF : NR;
  const int K   = (sl == 0) ? 8 : ((sl == 1) ? 4 : 6);
  const int tid = threadIdx.x;

  for (int i = tid; i < N; i += 256)
    p[i] = pooled[(size_t)b * NTOT + off + i];
  __syncthreads();

  for (int k = 0; k < K; ++k) {
    float bv = -2.0f;
    int bi = 1 << 30;
    for (int i = tid; i < N; i += 256) {
      float v = p[i];
      if (v > bv) { bv = v; bi = i; }
    }
    rv[tid] = bv; ri[tid] = bi;
    __syncthreads();
    for (int st = 128; st > 0; st >>= 1) {
      if (tid < st) {
        float v2 = rv[tid + st]; int i2 = ri[tid + st];
        if (v2 > rv[tid] || (v2 == rv[tid] && i2 < ri[tid])) {
          rv[tid] = v2; ri[tid] = i2;
        }
      }
      __syncthreads();
    }
    if (tid == 0) {
      vals[k] = rv[0]; idxs[k] = ri[0];
      p[ri[0]] = -1.0f;
    }
    __syncthreads();
  }

  if (tid == 0) {
    float s = 0.0f;
    for (int k = 0; k < K; ++k) s += vals[k];
    s_inv = 1.0f / (s + 1e-8f);
  }
  __syncthreads();

  float* ob = out + (size_t)b * (NF + 2 * NR + NT);
  if (sl == 0) {
    for (int i = tid; i < NF; i += 256) ob[i] = 0.0f;
  } else if (sl == 1) {
    for (int i = tid; i < NR; i += 256) { ob[NF + i] = 0.0f; ob[NF + NR + i] = 0.0f; }
  } else {
    for (int i = tid; i < NT; i += 256) ob[NF + 2 * NR + i] = 0.0f;
  }
  __syncthreads();
  if (tid < K) {
    float v = vals[tid] * s_inv;
    int ix = idxs[tid];
    if (sl == 0) {
      ob[ix] = v;
    } else if (sl == 1) {
      ob[NF + ix] = v;
      ob[NF + NR + ix] = v;
    } else {
      ob[NF + 2 * NR + ix] = v;
    }
  }
}

// ---------------------------------------------------------------------------
extern "C" void kernel_launch(void* const* d_in, const int* in_sizes, int n_in,
                              void* d_out, int out_size, void* d_ws, size_t ws_size,
                              hipStream_t stream) {
  const float* x    = (const float*)d_in[0];   // [B,S,D]
  const float* imp  = (const float*)d_in[1];   // [B,S]
  const float* W    = (const float*)d_in[2];   // [D,DS]
  const float* bias = (const float*)d_in[3];   // [DS]
  const float* emb  = (const float*)d_in[4];   // [NTOT,DS]
  float* out = (float*)d_out;

  // workspace layout
  unsigned short* eh  = (unsigned short*)d_ws;            // NTOT*64
  unsigned short* el  = eh  + (size_t)NTOT * DS;
  unsigned short* wth = el  + (size_t)NTOT * DS;          // 64*2048
  unsigned short* wtl = wth + (size_t)DS * DIM;
  unsigned short* hh  = wtl + (size_t)DS * DIM;           // TOK*64
  unsigned short* hl  = hh  + (size_t)TOK * DS;
  float* Zp     = (float*)(hl + (size_t)TOK * DS);        // TOK*16
  float* a      = Zp + (size_t)TOK * 16;                  // 3*TOK
  float* Bp     = a + 3 * (size_t)TOK;                    // 128*NTOT
  float* pooled = Bp + (size_t)128 * NTOT;                // 4*NTOT
  float* Hpart  = pooled + (size_t)BATCH * NTOT;          // 4*TOK*64

  size_t need = (2 * (size_t)NTOT * DS + 2 * (size_t)DS * DIM +
                 2 * (size_t)TOK * DS) * sizeof(unsigned short) +
                ((size_t)TOK * 16 + 3 * (size_t)TOK + 128 * (size_t)NTOT +
                 (size_t)BATCH * NTOT + (size_t)KSPLIT * TOK * DS) * sizeof(float);
  if (ws_size < need) return;   // ~28.6 MB (R2 proved ws >= 281 MB)

  k_prep_emb<<<NTOT / 4, 256, 0, stream>>>(emb, eh, el);
  k_prep_w<<<DS, 256, 0, stream>>>(W, wth, wtl);
  k_h<<<dim3(TOK / 64, KSPLIT), 256, 0, stream>>>(x, wth, wtl, Hpart);
  k_hc<<<TOK * 16 / 256, 256, 0, stream>>>(Hpart, bias, hh, hl);

  k_zle<0><<<dim3(128, 16), 256, 0, stream>>>(hh, hl, eh, el, nullptr, Zp, nullptr);
  k_a2<<<TOK / 256, 256, 0, stream>>>(Zp, imp, a);
  k_zle<2><<<dim3(128, 16), 256, 0, stream>>>(hh, hl, eh, el, a, nullptr, Bp);
  k_red<<<(BATCH * NTOT) / 256, 256, 0, stream>>>(Bp, pooled);
  k_topk<<<12, 256, 0, stream>>>(pooled, out);
}

// Round 8
// 190.375 us; speedup vs baseline: 1.4691x; 1.4691x over previous
//
#include <hip/hip_runtime.h>
#include <math.h>

// Problem constants
#define BATCH 4
#define SEQ   4096
#define DIM   2048
#define DS    64
#define NF    4096
#define NR    2048
#define NT    2048
#define NTOT  8192          // NF+NR+NT
#define TOK   16384         // BATCH*SEQ
#define KSPLIT 4

typedef __attribute__((ext_vector_type(8))) __bf16 bf16x8;
typedef __attribute__((ext_vector_type(4))) float  f32x4;

static __device__ __forceinline__ unsigned short f2bf(float x) {
  unsigned int u = __float_as_uint(x);
  u += 0x7fffu + ((u >> 16) & 1u);       // round-to-nearest-even
  return (unsigned short)(u >> 16);
}
static __device__ __forceinline__ float bf2f(unsigned int lo16) {
  return __uint_as_float(lo16 << 16);
}

// ---------------------------------------------------------------------------
// P0: normalized emb -> split bf16 (hi, lo), scale pre-applied.
// ---------------------------------------------------------------------------
__global__ __launch_bounds__(256) void k_prep_emb(const float* __restrict__ emb,
                                                  unsigned short* __restrict__ eh,
                                                  unsigned short* __restrict__ el) {
  int row  = blockIdx.x * 4 + (threadIdx.x >> 6);
  int lane = threadIdx.x & 63;
  float v  = emb[(size_t)row * DS + lane];
  float ss = v * v;
#pragma unroll
  for (int m = 32; m >= 1; m >>= 1) ss += __shfl_xor(ss, m, 64);
  float sc = 1.0f / fmaxf(sqrtf(ss), 1e-12f);
  float w  = v * sc;
  unsigned short hi = f2bf(w);
  eh[(size_t)row * DS + lane] = hi;
  el[(size_t)row * DS + lane] = f2bf(w - bf2f(hi));
}

// ---------------------------------------------------------------------------
// P1: W [2048][64] -> transposed split bf16 wt[c][k] (hi, lo)
// ---------------------------------------------------------------------------
__global__ __launch_bounds__(256) void k_prep_w(const float* __restrict__ W,
                                                unsigned short* __restrict__ wth,
                                                unsigned short* __restrict__ wtl) {
  int c = blockIdx.x;
#pragma unroll
  for (int it = 0; it < 8; ++it) {
    int k = threadIdx.x + it * 256;
    float v = W[(size_t)k * DS + c];
    unsigned short hi = f2bf(v);
    wth[(size_t)c * DIM + k] = hi;
    wtl[(size_t)c * DIM + k] = f2bf(v - bf2f(hi));
  }
}

// ---------------------------------------------------------------------------
// K1: h-partials = x @ W  (K-split 4, f32 partial out).
// grid (TOK/64, 4), 256 thr (4 waves), tile 64 tok x 64 col, K-step 32,
// double-buffered LDS + 2-deep register prefetch. 32 KB LDS.
// ---------------------------------------------------------------------------
__global__ __launch_bounds__(256) void k_h(
    const float* __restrict__ x, const unsigned short* __restrict__ wth,
    const unsigned short* __restrict__ wtl, float* __restrict__ Hpart) {
  __shared__ __align__(16) unsigned short xh[2][64 * 32];   // 4 KB each
  __shared__ __align__(16) unsigned short xl[2][64 * 32];
  __shared__ __align__(16) unsigned short wh[2][64 * 32];
  __shared__ __align__(16) unsigned short wl[2][64 * 32];   // 32 KB total
  const int tid  = threadIdx.x;
  const int t0   = blockIdx.x * 64;
  const int kbase = blockIdx.y * (DIM / KSPLIT);            // 512
  const int lane = tid & 63, wv = tid >> 6;
  const int fr   = lane & 15, oct = lane >> 4;

  float4 xrA[2], xrB[2];
  uint4  wrA[2], wrB[2];   // [0]=hi [1]=lo

  auto LOADX = [&](int k0, float4* xr, uint4* wr) {
#pragma unroll
    for (int it = 0; it < 2; ++it) {
      int idx = tid + it * 256;
      int r = idx >> 3, q = idx & 7;
      xr[it] = *reinterpret_cast<const float4*>(
          &x[(size_t)(t0 + r) * DIM + k0 + q * 4]);
    }
    int c = tid >> 2, s = tid & 3;
    size_t bo = ((size_t)c * DIM + k0 + s * 8) * 2;
    wr[0] = *reinterpret_cast<const uint4*>((const char*)wth + bo);
    wr[1] = *reinterpret_cast<const uint4*>((const char*)wtl + bo);
  };
  auto STORE = [&](int buf, float4* xr, uint4* wr) {
#pragma unroll
    for (int it = 0; it < 2; ++it) {
      int idx = tid + it * 256;
      int r = idx >> 3, q = idx & 7;
      int bo = (r * 64 + q * 8) ^ ((r & 3) << 4);
      float4 v = xr[it];
      unsigned short a0 = f2bf(v.x), a1 = f2bf(v.y), a2 = f2bf(v.z), a3 = f2bf(v.w);
      uint2 hi; hi.x = a0 | ((unsigned)a1 << 16); hi.y = a2 | ((unsigned)a3 << 16);
      *reinterpret_cast<uint2*>((char*)xh[buf] + bo) = hi;
      uint2 lo;
      lo.x = (unsigned)f2bf(v.x - bf2f(a0)) | ((unsigned)f2bf(v.y - bf2f(a1)) << 16);
      lo.y = (unsigned)f2bf(v.z - bf2f(a2)) | ((unsigned)f2bf(v.w - bf2f(a3)) << 16);
      *reinterpret_cast<uint2*>((char*)xl[buf] + bo) = lo;
    }
    int c = tid >> 2, s = tid & 3;
    int bo = (c * 64 + s * 16) ^ ((c & 3) << 4);
    *reinterpret_cast<uint4*>((char*)wh[buf] + bo) = wr[0];
    *reinterpret_cast<uint4*>((char*)wl[buf] + bo) = wr[1];
  };

  f32x4 acc[4];
#pragma unroll
  for (int j = 0; j < 4; ++j) acc[j] = (f32x4)0.0f;

  auto COMPUTE = [&](int buf) {
    int row = wv * 16 + fr;
    int boA = (row * 64 + oct * 16) ^ ((row & 3) << 4);
    bf16x8 ah  = *reinterpret_cast<const bf16x8*>((const char*)xh[buf] + boA);
    bf16x8 al_ = *reinterpret_cast<const bf16x8*>((const char*)xl[buf] + boA);
#pragma unroll
    for (int j = 0; j < 4; ++j) {
      int c = j * 16 + fr;
      int boB = (c * 64 + oct * 16) ^ ((c & 3) << 4);
      bf16x8 bh  = *reinterpret_cast<const bf16x8*>((const char*)wh[buf] + boB);
      bf16x8 bl_ = *reinterpret_cast<const bf16x8*>((const char*)wl[buf] + boB);
      acc[j] = __builtin_amdgcn_mfma_f32_16x16x32_bf16(ah,  bh,  acc[j], 0, 0, 0);
      acc[j] = __builtin_amdgcn_mfma_f32_16x16x32_bf16(ah,  bl_, acc[j], 0, 0, 0);
      acc[j] = __builtin_amdgcn_mfma_f32_16x16x32_bf16(al_, bh,  acc[j], 0, 0, 0);
    }
  };

  LOADX(kbase, xrA, wrA);
  LOADX(kbase + 32, xrB, wrB);
  for (int s = 0; s < 16; s += 2) {
    STORE(0, xrA, wrA);
    if (s + 2 < 16) LOADX(kbase + (s + 2) * 32, xrA, wrA);
    __syncthreads();
    COMPUTE(0);
    STORE(1, xrB, wrB);
    if (s + 3 < 16) LOADX(kbase + (s + 3) * 32, xrB, wrB);
    __syncthreads();
    COMPUTE(1);
  }

  // C layout: col = lane&15, row = oct*4 + reg [m89]
  float* op = Hpart + (size_t)blockIdx.y * TOK * DS;
#pragma unroll
  for (int j = 0; j < 4; ++j) {
    int c = j * 16 + fr;
#pragma unroll
    for (int r = 0; r < 4; ++r) {
      int t = t0 + wv * 16 + oct * 4 + r;
      op[(size_t)t * DS + c] = acc[j][r];
    }
  }
}

// ---------------------------------------------------------------------------
// K1b: combine 4 K-split partials + bias -> split bf16 h.
// ---------------------------------------------------------------------------
__global__ __launch_bounds__(256) void k_hc(const float* __restrict__ Hpart,
                                            const float* __restrict__ bias,
                                            unsigned short* __restrict__ hh,
                                            unsigned short* __restrict__ hl) {
  int idx = blockIdx.x * 256 + threadIdx.x;   // 0..TOK*16-1
  int t = idx >> 4, q = idx & 15;
  size_t o = (size_t)t * DS + q * 4;
  float4 s0 = *reinterpret_cast<const float4*>(&Hpart[o]);
  float4 s1 = *reinterpret_cast<const float4*>(&Hpart[(size_t)TOK * DS + o]);
  float4 s2 = *reinterpret_cast<const float4*>(&Hpart[2 * (size_t)TOK * DS + o]);
  float4 s3 = *reinterpret_cast<const float4*>(&Hpart[3 * (size_t)TOK * DS + o]);
  float4 bv = *reinterpret_cast<const float4*>(&bias[q * 4]);
  float v0 = (s0.x + s1.x) + (s2.x + s3.x) + bv.x;
  float v1 = (s0.y + s1.y) + (s2.y + s3.y) + bv.y;
  float v2 = (s0.z + s1.z) + (s2.z + s3.z) + bv.z;
  float v3 = (s0.w + s1.w) + (s2.w + s3.w) + bv.w;
  unsigned short h0 = f2bf(v0), h1 = f2bf(v1), h2 = f2bf(v2), h3 = f2bf(v3);
  uint2 hi; hi.x = h0 | ((unsigned)h1 << 16); hi.y = h2 | ((unsigned)h3 << 16);
  uint2 lo;
  lo.x = (unsigned)f2bf(v0 - bf2f(h0)) | ((unsigned)f2bf(v1 - bf2f(h1)) << 16);
  lo.y = (unsigned)f2bf(v2 - bf2f(h2)) | ((unsigned)f2bf(v3 - bf2f(h3)) << 16);
  *reinterpret_cast<uint2*>(&hh[o]) = hi;
  *reinterpret_cast<uint2*>(&hl[o]) = lo;
}

// ---------------------------------------------------------------------------
// K2: logits GEMM via split-bf16 MFMA, fused epilogues.
// block: 128 tok x 512 neurons (4 subtiles of 128), 256 thr (4 waves).
// h (4MB, L2-resident) is NOT LDS-staged: A-fragments load direct from
// global (16B/lane). Only the e-subtile lives in LDS (32KB + 2KB reduce)
// -> 3 blocks/CU via __launch_bounds__(256,3): inter-block phase overlap.
// MODE 0: Zp[t*16+cb] = sum_n exp(logit)
// MODE 2: Bp[tb*NTOT+n] = sum_t a[sl][t] * exp(logit)
// ---------------------------------------------------------------------------
template<int MODE>
__global__ __launch_bounds__(256, 3) void k_zle(
    const unsigned short* __restrict__ hh, const unsigned short* __restrict__ hl,
    const unsigned short* __restrict__ eh, const unsigned short* __restrict__ el,
    const float* __restrict__ a, float* __restrict__ Zp, float* __restrict__ Bp) {
  __shared__ __align__(16) unsigned short esh[128 * 64];   // 16 KB
  __shared__ __align__(16) unsigned short esl[128 * 64];   // 16 KB
  __shared__ float red2[512];                              // 2 KB (MODE2)
  const int tid = threadIdx.x;
  const int tb  = blockIdx.x;          // token block 0..127
  const int cb  = blockIdx.y;          // 512-neuron block 0..15
  const int t0  = tb * 128;

  const int lane = tid & 63;
  const int wv   = tid >> 6;
  const int fr   = lane & 15;
  const int oct  = lane >> 4;

  // ---- A fragments: direct global loads (hh/hl are L2-resident) ----
  bf16x8 ah[2][2], al[2][2];
#pragma unroll
  for (int i = 0; i < 2; ++i)
#pragma unroll
    for (int kh = 0; kh < 2; ++kh) {
      size_t off = (size_t)(t0 + wv * 32 + i * 16 + fr) * DS + kh * 32 + oct * 8;
      ah[i][kh] = *reinterpret_cast<const bf16x8*>(hh + off);
      al[i][kh] = *reinterpret_cast<const bf16x8*>(hl + off);
    }

  float av[2][4];
  if (MODE == 2) {
    const int sl = (cb < 8) ? 0 : ((cb < 12) ? 1 : 2);
#pragma unroll
    for (int i = 0; i < 2; ++i)
#pragma unroll
      for (int r = 0; r < 4; ++r)
        av[i][r] = a[(size_t)sl * TOK + t0 + wv * 32 + i * 16 + oct * 4 + r];
  }
  float rs[2][4];
#pragma unroll
  for (int i = 0; i < 2; ++i)
#pragma unroll
    for (int r = 0; r < 4; ++r) rs[i][r] = 0.0f;

  for (int sub = 0; sub < 4; ++sub) {
    const int n0 = cb * 512 + sub * 128;
    if (sub) __syncthreads();          // prior esh/esl reads complete
    // ---- stage e subtile (pure copies) ----
#pragma unroll
    for (int it = 0; it < 4; ++it) {
      int idx = tid + it * 256;
      int r = idx >> 3, k8 = idx & 7;
      int bo = (r * 128 + k8 * 16) ^ ((r & 7) << 4);
      *reinterpret_cast<uint4*>((char*)esh + bo) =
          *reinterpret_cast<const uint4*>((const char*)eh + (size_t)(n0 + r) * 128 + k8 * 16);
      *reinterpret_cast<uint4*>((char*)esl + bo) =
          *reinterpret_cast<const uint4*>((const char*)el + (size_t)(n0 + r) * 128 + k8 * 16);
    }
    __syncthreads();

    f32x4 acc[2][8];
#pragma unroll
    for (int i = 0; i < 2; ++i)
#pragma unroll
      for (int j = 0; j < 8; ++j) acc[i][j] = (f32x4)0.0f;

#pragma unroll
    for (int j = 0; j < 8; ++j) {
      int col = j * 16 + fr;
      bf16x8 bh[2], bl[2];
#pragma unroll
      for (int kh = 0; kh < 2; ++kh) {
        int bo = (col * 128 + (kh * 32 + oct * 8) * 2) ^ ((col & 7) << 4);
        bh[kh] = *reinterpret_cast<const bf16x8*>((const char*)esh + bo);
        bl[kh] = *reinterpret_cast<const bf16x8*>((const char*)esl + bo);
      }
#pragma unroll
      for (int i = 0; i < 2; ++i) {
#pragma unroll
        for (int kh = 0; kh < 2; ++kh) {
          acc[i][j] = __builtin_amdgcn_mfma_f32_16x16x32_bf16(ah[i][kh], bh[kh], acc[i][j], 0, 0, 0);
          acc[i][j] = __builtin_amdgcn_mfma_f32_16x16x32_bf16(ah[i][kh], bl[kh], acc[i][j], 0, 0, 0);
          acc[i][j] = __builtin_amdgcn_mfma_f32_16x16x32_bf16(al[i][kh], bh[kh], acc[i][j], 0, 0, 0);
        }
      }
    }
    // C/D layout: col = lane&15, row = oct*4 + reg [m89]

    if (MODE == 0) {
#pragma unroll
      for (int i = 0; i < 2; ++i)
#pragma unroll
        for (int j = 0; j < 8; ++j)
#pragma unroll
          for (int r = 0; r < 4; ++r) rs[i][r] += __expf(acc[i][j][r]);
    } else {
      float cs[8];
#pragma unroll
      for (int j = 0; j < 8; ++j) {
        float s = 0.0f;
#pragma unroll
        for (int i = 0; i < 2; ++i)
#pragma unroll
          for (int r = 0; r < 4; ++r) s = fmaf(av[i][r], __expf(acc[i][j][r]), s);
        cs[j] = s;
      }
#pragma unroll
      for (int j = 0; j < 8; ++j) {
        cs[j] += __shfl_xor(cs[j], 16, 64);
        cs[j] += __shfl_xor(cs[j], 32, 64);
      }
      if (oct == 0) {
#pragma unroll
        for (int j = 0; j < 8; ++j) red2[wv * 128 + j * 16 + fr] = cs[j];
      }
      __syncthreads();
      if (tid < 128) {
        float v = red2[tid] + red2[128 + tid] + red2[256 + tid] + red2[384 + tid];
        Bp[(size_t)tb * NTOT + n0 + tid] = v;
      }
      // next iteration's top barrier protects red2 before its next write
    }
  }

  if (MODE == 0) {
#pragma unroll
    for (int m = 1; m < 16; m <<= 1)
#pragma unroll
      for (int i = 0; i < 2; ++i)
#pragma unroll
        for (int r = 0; r < 4; ++r) rs[i][r] += __shfl_xor(rs[i][r], m, 64);
    if (fr == 0) {
#pragma unroll
      for (int i = 0; i < 2; ++i)
#pragma unroll
        for (int r = 0; r < 4; ++r) {
          int t = t0 + wv * 32 + i * 16 + oct * 4 + r;
          Zp[(size_t)t * 16 + cb] = rs[i][r];
        }
    }
  }
}

// ---------------------------------------------------------------------------
// K3: combine 16 Zp partials per token into a[slice][t] = imp_t / Z_slice
// ---------------------------------------------------------------------------
__global__ __launch_bounds__(256) void k_a2(const float* __restrict__ Zp,
                                            const float* __restrict__ imp,
                                            float* __restrict__ a) {
  int t = blockIdx.x * 256 + threadIdx.x;
  const float4* zp = reinterpret_cast<const float4*>(&Zp[(size_t)t * 16]);
  float4 q0 = zp[0], q1 = zp[1], q2 = zp[2], q3 = zp[3];
  float zf = ((q0.x + q0.y) + (q0.z + q0.w)) + ((q1.x + q1.y) + (q1.z + q1.w));
  float zr = (q2.x + q2.y) + (q2.z + q2.w);
  float zt = (q3.x + q3.y) + (q3.z + q3.w);
  float im = imp[t];
  a[t]           = im / zf;
  a[TOK + t]     = im / zr;
  a[2 * TOK + t] = im / zt;
}

// ---------------------------------------------------------------------------
// K4: reduce the 32 token-block partials -> pooled[b][n].
// ---------------------------------------------------------------------------
__global__ __launch_bounds__(256) void k_red(const float* __restrict__ Bp,
                                             float* __restrict__ pooled) {
  int idx = blockIdx.x * 256 + threadIdx.x;   // 0 .. BATCH*NTOT-1
  int b = idx >> 13;                          // /NTOT
  int n = idx & (NTOT - 1);
  const float* src = Bp + (size_t)(b * 32) * NTOT + n;
  float s = 0.0f;
#pragma unroll
  for (int g = 0; g < 32; ++g) s += src[(size_t)g * NTOT];
  pooled[idx] = s;
}

// ---------------------------------------------------------------------------
// K5: per (batch, slice): top-k over pooled, renorm, scatter.
// ---------------------------------------------------------------------------
__global__ __launch_bounds__(256) void k_topk(const float* __restrict__ pooled,
                                              float* __restrict__ out) {
  __shared__ float p[4096];
  __shared__ float rv[256];
  __shared__ int   ri[256];
  __shared__ float vals[8];
  __shared__ int   idxs[8];
  __shared__ float s_inv;

  const int bid = blockIdx.x;
  const int b   = bid / 3;
  const int sl  = bid % 3;
  const int off = (sl == 0) ? 0 : ((sl == 1) ? NF : NF + NR);
  const int N   = (sl == 0) ? NF : NR;
  const int K   = (sl == 0) ? 8 : ((sl == 1) ? 4 : 6);
  const int tid = threadIdx.x;

  for (int i = tid; i < N; i += 256)
    p[i] = pooled[(size_t)b * NTOT + off + i];
  __syncthreads();

  for (int k = 0; k < K; ++k) {
    float bv = -2.0f;
    int bi = 1 << 30;
    for (int i = tid; i < N; i += 256) {
      float v = p[i];
      if (v > bv) { bv = v; bi = i; }
    }
    rv[tid] = bv; ri[tid] = bi;
    __syncthreads();
    for (int st = 128; st > 0; st >>= 1) {
      if (tid < st) {
        float v2 = rv[tid + st]; int i2 = ri[tid + st];
        if (v2 > rv[tid] || (v2 == rv[tid] && i2 < ri[tid])) {
          rv[tid] = v2; ri[tid] = i2;
        }
      }
      __syncthreads();
    }
    if (tid == 0) {
      vals[k] = rv[0]; idxs[k] = ri[0];
      p[ri[0]] = -1.0f;
    }
    __syncthreads();
  }

  if (tid == 0) {
    float s = 0.0f;
    for (int k = 0; k < K; ++k) s += vals[k];
    s_inv = 1.0f / (s + 1e-8f);
  }
  __syncthreads();

  float* ob = out + (size_t)b * (NF + 2 * NR + NT);
  if (sl == 0) {
    for (int i = tid; i < NF; i += 256) ob[i] = 0.0f;
  } else if (sl == 1) {
    for (int i = tid; i < NR; i += 256) { ob[NF + i] = 0.0f; ob[NF + NR + i] = 0.0f; }
  } else {
    for (int i = tid; i < NT; i += 256) ob[NF + 2 * NR + i] = 0.0f;
  }
  __syncthreads();
  if (tid < K) {
    float v = vals[tid] * s_inv;
    int ix = idxs[tid];
    if (sl == 0) {
      ob[ix] = v;
    } else if (sl == 1) {
      ob[NF + ix] = v;
      ob[NF + NR + ix] = v;
    } else {
      ob[NF + 2 * NR + ix] = v;
    }
  }
}

// ---------------------------------------------------------------------------
extern "C" void kernel_launch(void* const* d_in, const int* in_sizes, int n_in,
                              void* d_out, int out_size, void* d_ws, size_t ws_size,
                              hipStream_t stream) {
  const float* x    = (const float*)d_in[0];   // [B,S,D]
  const float* imp  = (const float*)d_in[1];   // [B,S]
  const float* W    = (const float*)d_in[2];   // [D,DS]
  const float* bias = (const float*)d_in[3];   // [DS]
  const float* emb  = (const float*)d_in[4];   // [NTOT,DS]
  float* out = (float*)d_out;

  // workspace layout
  unsigned short* eh  = (unsigned short*)d_ws;            // NTOT*64
  unsigned short* el  = eh  + (size_t)NTOT * DS;
  unsigned short* wth = el  + (size_t)NTOT * DS;          // 64*2048
  unsigned short* wtl = wth + (size_t)DS * DIM;
  unsigned short* hh  = wtl + (size_t)DS * DIM;           // TOK*64
  unsigned short* hl  = hh  + (size_t)TOK * DS;
  float* Zp     = (float*)(hl + (size_t)TOK * DS);        // TOK*16
  float* a      = Zp + (size_t)TOK * 16;                  // 3*TOK
  float* Bp     = a + 3 * (size_t)TOK;                    // 128*NTOT
  float* pooled = Bp + (size_t)128 * NTOT;                // 4*NTOT
  float* Hpart  = pooled + (size_t)BATCH * NTOT;          // 4*TOK*64

  size_t need = (2 * (size_t)NTOT * DS + 2 * (size_t)DS * DIM +
                 2 * (size_t)TOK * DS) * sizeof(unsigned short) +
                ((size_t)TOK * 16 + 3 * (size_t)TOK + 128 * (size_t)NTOT +
                 (size_t)BATCH * NTOT + (size_t)KSPLIT * TOK * DS) * sizeof(float);
  if (ws_size < need) return;   // ~28.6 MB (R2 proved ws >= 281 MB)

  k_prep_emb<<<NTOT / 4, 256, 0, stream>>>(emb, eh, el);
  k_prep_w<<<DS, 256, 0, stream>>>(W, wth, wtl);
  k_h<<<dim3(TOK / 64, KSPLIT), 256, 0, stream>>>(x, wth, wtl, Hpart);
  k_hc<<<TOK * 16 / 256, 256, 0, stream>>>(Hpart, bias, hh, hl);

  k_zle<0><<<dim3(128, 16), 256, 0, stream>>>(hh, hl, eh, el, nullptr, Zp, nullptr);
  k_a2<<<TOK / 256, 256, 0, stream>>>(Zp, imp, a);
  k_zle<2><<<dim3(128, 16), 256, 0, stream>>>(hh, hl, eh, el, a, nullptr, Bp);
  k_red<<<(BATCH * NTOT) / 256, 256, 0, stream>>>(Bp, pooled);
  k_topk<<<12, 256, 0, stream>>>(pooled, out);
}

// Round 9
// 170.016 us; speedup vs baseline: 1.6450x; 1.1198x over previous
//
#include <hip/hip_runtime.h>
#include <math.h>

// Problem constants
#define BATCH 4
#define SEQ   4096
#define DIM   2048
#define DS    64
#define NF    4096
#define NR    2048
#define NT    2048
#define NTOT  8192          // NF+NR+NT
#define TOK   16384         // BATCH*SEQ
#define KSPLIT 8
#define KS    (DIM / KSPLIT)   // 256

typedef __attribute__((ext_vector_type(8))) __bf16 bf16x8;
typedef __attribute__((ext_vector_type(4))) float  f32x4;

static __device__ __forceinline__ unsigned short f2bf(float x) {
  unsigned int u = __float_as_uint(x);
  u += 0x7fffu + ((u >> 16) & 1u);       // round-to-nearest-even
  return (unsigned short)(u >> 16);
}
static __device__ __forceinline__ float bf2f(unsigned int lo16) {
  return __uint_as_float(lo16 << 16);
}

// split 8 f32 into hi/lo bf16x8
static __device__ __forceinline__ void split8(const float4& a, const float4& b,
                                              bf16x8& hi, bf16x8& lo) {
  float v[8] = {a.x, a.y, a.z, a.w, b.x, b.y, b.z, b.w};
  union { unsigned short u[8]; bf16x8 v8; } H, L;
#pragma unroll
  for (int i = 0; i < 8; ++i) {
    unsigned short h = f2bf(v[i]);
    H.u[i] = h;
    L.u[i] = f2bf(v[i] - bf2f(h));
  }
  hi = H.v8; lo = L.v8;
}

// ---------------------------------------------------------------------------
// P0: normalized emb -> split bf16 (hi, lo), scale pre-applied.
// ---------------------------------------------------------------------------
__global__ __launch_bounds__(256) void k_prep_emb(const float* __restrict__ emb,
                                                  unsigned short* __restrict__ eh,
                                                  unsigned short* __restrict__ el) {
  int row  = blockIdx.x * 4 + (threadIdx.x >> 6);
  int lane = threadIdx.x & 63;
  float v  = emb[(size_t)row * DS + lane];
  float ss = v * v;
#pragma unroll
  for (int m = 32; m >= 1; m >>= 1) ss += __shfl_xor(ss, m, 64);
  float sc = 1.0f / fmaxf(sqrtf(ss), 1e-12f);
  float w  = v * sc;
  unsigned short hi = f2bf(w);
  eh[(size_t)row * DS + lane] = hi;
  el[(size_t)row * DS + lane] = f2bf(w - bf2f(hi));
}

// ---------------------------------------------------------------------------
// P1: W [2048][64] -> transposed split bf16 wt[c][k] (hi, lo)
// ---------------------------------------------------------------------------
__global__ __launch_bounds__(256) void k_prep_w(const float* __restrict__ W,
                                                unsigned short* __restrict__ wth,
                                                unsigned short* __restrict__ wtl) {
  int c = blockIdx.x;
#pragma unroll
  for (int it = 0; it < 8; ++it) {
    int k = threadIdx.x + it * 256;
    float v = W[(size_t)k * DS + c];
    unsigned short hi = f2bf(v);
    wth[(size_t)c * DIM + k] = hi;
    wtl[(size_t)c * DIM + k] = f2bf(v - bf2f(hi));
  }
}

// ---------------------------------------------------------------------------
// K1: h-partials = x @ W  (K-split 8, f32 partial out).
// grid (TOK/128, 8), 512 thr (8 waves), wave = 16 tok x 64 col.
// W slice staged in LDS ONCE (64 KB, swizzled) -> zero barriers in K-loop.
// x A-fragments load DIRECT from global (full 128B lines: 4 octs x 32B/row),
// split to bf16 hi/lo in regs, 1-step prefetch. 2 blocks/CU = 4 waves/SIMD.
// ---------------------------------------------------------------------------
__global__ __launch_bounds__(512) void k_h(
    const float* __restrict__ x, const unsigned short* __restrict__ wth,
    const unsigned short* __restrict__ wtl, float* __restrict__ Hpart) {
  __shared__ __align__(16) unsigned short wsh[64 * KS];   // 32 KB
  __shared__ __align__(16) unsigned short wsl[64 * KS];   // 32 KB
  const int tid   = threadIdx.x;
  const int t0    = blockIdx.x * 128;
  const int kbase = blockIdx.y * KS;
  const int lane  = tid & 63, wv = tid >> 6;   // 8 waves
  const int fr    = lane & 15, oct = lane >> 4;

  // ---- stage W slice once: 64 cols x 256 k (hi+lo), XOR-swizzled ----
#pragma unroll
  for (int it = 0; it < 4; ++it) {
    int idx = tid + it * 512;          // 0..2047 uint4 slots
    int c = idx >> 5, k16 = idx & 31;  // col, 16B-chunk within col
    int bo = (c * 512 + k16 * 16) ^ ((c & 7) << 4);
    size_t src = ((size_t)c * DIM + kbase) * 2 + (size_t)k16 * 16;
    *reinterpret_cast<uint4*>((char*)wsh + bo) =
        *reinterpret_cast<const uint4*>((const char*)wth + src);
    *reinterpret_cast<uint4*>((char*)wsl + bo) =
        *reinterpret_cast<const uint4*>((const char*)wtl + src);
  }
  __syncthreads();

  const float* xp = x + (size_t)(t0 + wv * 16 + fr) * DIM + kbase + oct * 8;

  f32x4 acc[4];
#pragma unroll
  for (int j = 0; j < 4; ++j) acc[j] = (f32x4)0.0f;

  float4 xa = *reinterpret_cast<const float4*>(xp);
  float4 xb = *reinterpret_cast<const float4*>(xp + 4);

#pragma unroll
  for (int s = 0; s < KS / 32; ++s) {     // 8 steps, no barriers
    bf16x8 ah, al;
    split8(xa, xb, ah, al);
    if (s + 1 < KS / 32) {               // prefetch next k-chunk
      xa = *reinterpret_cast<const float4*>(xp + (s + 1) * 32);
      xb = *reinterpret_cast<const float4*>(xp + (s + 1) * 32 + 4);
    }
#pragma unroll
    for (int j = 0; j < 4; ++j) {
      int col = j * 16 + fr;
      int bo = (col * 512 + s * 64 + oct * 16) ^ ((col & 7) << 4);
      bf16x8 bh = *reinterpret_cast<const bf16x8*>((const char*)wsh + bo);
      bf16x8 bl = *reinterpret_cast<const bf16x8*>((const char*)wsl + bo);
      acc[j] = __builtin_amdgcn_mfma_f32_16x16x32_bf16(ah, bh, acc[j], 0, 0, 0);
      acc[j] = __builtin_amdgcn_mfma_f32_16x16x32_bf16(ah, bl, acc[j], 0, 0, 0);
      acc[j] = __builtin_amdgcn_mfma_f32_16x16x32_bf16(al, bh, acc[j], 0, 0, 0);
    }
  }

  // C layout: col = lane&15, row = oct*4 + reg [m89]
  float* op = Hpart + (size_t)blockIdx.y * TOK * DS;
#pragma unroll
  for (int j = 0; j < 4; ++j) {
    int c = j * 16 + fr;
#pragma unroll
    for (int r = 0; r < 4; ++r) {
      int t = t0 + wv * 16 + oct * 4 + r;
      op[(size_t)t * DS + c] = acc[j][r];
    }
  }
}

// ---------------------------------------------------------------------------
// K1b: combine 8 K-split partials + bias -> split bf16 h.
// ---------------------------------------------------------------------------
__global__ __launch_bounds__(256) void k_hc(const float* __restrict__ Hpart,
                                            const float* __restrict__ bias,
                                            unsigned short* __restrict__ hh,
                                            unsigned short* __restrict__ hl) {
  int idx = blockIdx.x * 256 + threadIdx.x;   // 0..TOK*16-1
  int t = idx >> 4, q = idx & 15;
  size_t o = (size_t)t * DS + q * 4;
  float4 bv = *reinterpret_cast<const float4*>(&bias[q * 4]);
  float v0 = bv.x, v1 = bv.y, v2 = bv.z, v3 = bv.w;
#pragma unroll
  for (int p = 0; p < KSPLIT; ++p) {
    float4 s = *reinterpret_cast<const float4*>(&Hpart[(size_t)p * TOK * DS + o]);
    v0 += s.x; v1 += s.y; v2 += s.z; v3 += s.w;
  }
  unsigned short h0 = f2bf(v0), h1 = f2bf(v1), h2 = f2bf(v2), h3 = f2bf(v3);
  uint2 hi; hi.x = h0 | ((unsigned)h1 << 16); hi.y = h2 | ((unsigned)h3 << 16);
  uint2 lo;
  lo.x = (unsigned)f2bf(v0 - bf2f(h0)) | ((unsigned)f2bf(v1 - bf2f(h1)) << 16);
  lo.y = (unsigned)f2bf(v2 - bf2f(h2)) | ((unsigned)f2bf(v3 - bf2f(h3)) << 16);
  *reinterpret_cast<uint2*>(&hh[o]) = hi;
  *reinterpret_cast<uint2*>(&hl[o]) = lo;
}

// ---------------------------------------------------------------------------
// K2: logits GEMM via split-bf16 MFMA, fused epilogues.
// block: 128 tok x 512 neurons (4 subtiles of 128), 256 thr (4 waves).
// h (4MB, L2-resident) NOT LDS-staged: A-fragments direct from global.
// Only e-subtile in LDS (32KB + 2KB) -> 3 blocks/CU.
// MODE 0: Zp[t*16+cb] = sum_n exp(logit)
// MODE 2: Bp[tb*NTOT+n] = sum_t a[sl][t] * exp(logit)
// ---------------------------------------------------------------------------
template<int MODE>
__global__ __launch_bounds__(256, 3) void k_zle(
    const unsigned short* __restrict__ hh, const unsigned short* __restrict__ hl,
    const unsigned short* __restrict__ eh, const unsigned short* __restrict__ el,
    const float* __restrict__ a, float* __restrict__ Zp, float* __restrict__ Bp) {
  __shared__ __align__(16) unsigned short esh[128 * 64];   // 16 KB
  __shared__ __align__(16) unsigned short esl[128 * 64];   // 16 KB
  __shared__ float red2[512];                              // 2 KB (MODE2)
  const int tid = threadIdx.x;
  const int tb  = blockIdx.x;          // token block 0..127
  const int cb  = blockIdx.y;          // 512-neuron block 0..15
  const int t0  = tb * 128;

  const int lane = tid & 63;
  const int wv   = tid >> 6;
  const int fr   = lane & 15;
  const int oct  = lane >> 4;

  // ---- A fragments: direct global loads (hh/hl are L2-resident) ----
  bf16x8 ah[2][2], al[2][2];
#pragma unroll
  for (int i = 0; i < 2; ++i)
#pragma unroll
    for (int kh = 0; kh < 2; ++kh) {
      size_t off = (size_t)(t0 + wv * 32 + i * 16 + fr) * DS + kh * 32 + oct * 8;
      ah[i][kh] = *reinterpret_cast<const bf16x8*>(hh + off);
      al[i][kh] = *reinterpret_cast<const bf16x8*>(hl + off);
    }

  float av[2][4];
  if (MODE == 2) {
    const int sl = (cb < 8) ? 0 : ((cb < 12) ? 1 : 2);
#pragma unroll
    for (int i = 0; i < 2; ++i)
#pragma unroll
      for (int r = 0; r < 4; ++r)
        av[i][r] = a[(size_t)sl * TOK + t0 + wv * 32 + i * 16 + oct * 4 + r];
  }
  float rs[2][4];
#pragma unroll
  for (int i = 0; i < 2; ++i)
#pragma unroll
    for (int r = 0; r < 4; ++r) rs[i][r] = 0.0f;

  for (int sub = 0; sub < 4; ++sub) {
    const int n0 = cb * 512 + sub * 128;
    if (sub) __syncthreads();          // prior esh/esl reads complete
    // ---- stage e subtile (pure copies) ----
#pragma unroll
    for (int it = 0; it < 4; ++it) {
      int idx = tid + it * 256;
      int r = idx >> 3, k8 = idx & 7;
      int bo = (r * 128 + k8 * 16) ^ ((r & 7) << 4);
      *reinterpret_cast<uint4*>((char*)esh + bo) =
          *reinterpret_cast<const uint4*>((const char*)eh + (size_t)(n0 + r) * 128 + k8 * 16);
      *reinterpret_cast<uint4*>((char*)esl + bo) =
          *reinterpret_cast<const uint4*>((const char*)el + (size_t)(n0 + r) * 128 + k8 * 16);
    }
    __syncthreads();

    f32x4 acc[2][8];
#pragma unroll
    for (int i = 0; i < 2; ++i)
#pragma unroll
      for (int j = 0; j < 8; ++j) acc[i][j] = (f32x4)0.0f;

#pragma unroll
    for (int j = 0; j < 8; ++j) {
      int col = j * 16 + fr;
      bf16x8 bh[2], bl[2];
#pragma unroll
      for (int kh = 0; kh < 2; ++kh) {
        int bo = (col * 128 + (kh * 32 + oct * 8) * 2) ^ ((col & 7) << 4);
        bh[kh] = *reinterpret_cast<const bf16x8*>((const char*)esh + bo);
        bl[kh] = *reinterpret_cast<const bf16x8*>((const char*)esl + bo);
      }
#pragma unroll
      for (int i = 0; i < 2; ++i) {
#pragma unroll
        for (int kh = 0; kh < 2; ++kh) {
          acc[i][j] = __builtin_amdgcn_mfma_f32_16x16x32_bf16(ah[i][kh], bh[kh], acc[i][j], 0, 0, 0);
          acc[i][j] = __builtin_amdgcn_mfma_f32_16x16x32_bf16(ah[i][kh], bl[kh], acc[i][j], 0, 0, 0);
          acc[i][j] = __builtin_amdgcn_mfma_f32_16x16x32_bf16(al[i][kh], bh[kh], acc[i][j], 0, 0, 0);
        }
      }
    }
    // C/D layout: col = lane&15, row = oct*4 + reg [m89]

    if (MODE == 0) {
#pragma unroll
      for (int i = 0; i < 2; ++i)
#pragma unroll
        for (int j = 0; j < 8; ++j)
#pragma unroll
          for (int r = 0; r < 4; ++r) rs[i][r] += __expf(acc[i][j][r]);
    } else {
      float cs[8];
#pragma unroll
      for (int j = 0; j < 8; ++j) {
        float s = 0.0f;
#pragma unroll
        for (int i = 0; i < 2; ++i)
#pragma unroll
          for (int r = 0; r < 4; ++r) s = fmaf(av[i][r], __expf(acc[i][j][r]), s);
        cs[j] = s;
      }
#pragma unroll
      for (int j = 0; j < 8; ++j) {
        cs[j] += __shfl_xor(cs[j], 16, 64);
        cs[j] += __shfl_xor(cs[j], 32, 64);
      }
      if (oct == 0) {
#pragma unroll
        for (int j = 0; j < 8; ++j) red2[wv * 128 + j * 16 + fr] = cs[j];
      }
      __syncthreads();
      if (tid < 128) {
        float v = red2[tid] + red2[128 + tid] + red2[256 + tid] + red2[384 + tid];
        Bp[(size_t)tb * NTOT + n0 + tid] = v;
      }
      // next iteration's top barrier protects red2 before its next write
    }
  }

  if (MODE == 0) {
#pragma unroll
    for (int m = 1; m < 16; m <<= 1)
#pragma unroll
      for (int i = 0; i < 2; ++i)
#pragma unroll
        for (int r = 0; r < 4; ++r) rs[i][r] += __shfl_xor(rs[i][r], m, 64);
    if (fr == 0) {
#pragma unroll
      for (int i = 0; i < 2; ++i)
#pragma unroll
        for (int r = 0; r < 4; ++r) {
          int t = t0 + wv * 32 + i * 16 + oct * 4 + r;
          Zp[(size_t)t * 16 + cb] = rs[i][r];
        }
    }
  }
}

// ---------------------------------------------------------------------------
// K3: combine 16 Zp partials per token into a[slice][t] = imp_t / Z_slice
// ---------------------------------------------------------------------------
__global__ __launch_bounds__(256) void k_a2(const float* __restrict__ Zp,
                                            const float* __restrict__ imp,
                                            float* __restrict__ a) {
  int t = blockIdx.x * 256 + threadIdx.x;
  const float4* zp = reinterpret_cast<const float4*>(&Zp[(size_t)t * 16]);
  float4 q0 = zp[0], q1 = zp[1], q2 = zp[2], q3 = zp[3];
  float zf = ((q0.x + q0.y) + (q0.z + q0.w)) + ((q1.x + q1.y) + (q1.z + q1.w));
  float zr = (q2.x + q2.y) + (q2.z + q2.w);
  float zt = (q3.x + q3.y) + (q3.z + q3.w);
  float im = imp[t];
  a[t]           = im / zf;
  a[TOK + t]     = im / zr;
  a[2 * TOK + t] = im / zt;
}

// ---------------------------------------------------------------------------
// K4: reduce the 32 token-block partials -> pooled[b][n].
// ---------------------------------------------------------------------------
__global__ __launch_bounds__(256) void k_red(const float* __restrict__ Bp,
                                             float* __restrict__ pooled) {
  int idx = blockIdx.x * 256 + threadIdx.x;   // 0 .. BATCH*NTOT-1
  int b = idx >> 13;                          // /NTOT
  int n = idx & (NTOT - 1);
  const float* src = Bp + (size_t)(b * 32) * NTOT + n;
  float s = 0.0f;
#pragma unroll
  for (int g = 0; g < 32; ++g) s += src[(size_t)g * NTOT];
  pooled[idx] = s;
}

// ---------------------------------------------------------------------------
// K5: per (batch, slice): top-k over pooled, renorm, scatter.
// ---------------------------------------------------------------------------
__global__ __launch_bounds__(256) void k_topk(const float* __restrict__ pooled,
                                              float* __restrict__ out) {
  __shared__ float p[4096];
  __shared__ float rv[256];
  __shared__ int   ri[256];
  __shared__ float vals[8];
  __shared__ int   idxs[8];
  __shared__ float s_inv;

  const int bid = blockIdx.x;
  const int b   = bid / 3;
  const int sl  = bid % 3;
  const int off = (sl == 0) ? 0 : ((sl == 1) ? NF : NF + NR);
  const int N   = (sl == 0) ? NF : NR;
  const int K   = (sl == 0) ? 8 : ((sl == 1) ? 4 : 6);
  const int tid = threadIdx.x;

  for (int i = tid; i < N; i += 256)
    p[i] = pooled[(size_t)b * NTOT + off + i];
  __syncthreads();

  for (int k = 0; k < K; ++k) {
    float bv = -2.0f;
    int bi = 1 << 30;
    for (int i = tid; i < N; i += 256) {
      float v = p[i];
      if (v > bv) { bv = v; bi = i; }
    }
    rv[tid] = bv; ri[tid] = bi;
    __syncthreads();
    for (int st = 128; st > 0; st >>= 1) {
      if (tid < st) {
        float v2 = rv[tid + st]; int i2 = ri[tid + st];
        if (v2 > rv[tid] || (v2 == rv[tid] && i2 < ri[tid])) {
          rv[tid] = v2; ri[tid] = i2;
        }
      }
      __syncthreads();
    }
    if (tid == 0) {
      vals[k] = rv[0]; idxs[k] = ri[0];
      p[ri[0]] = -1.0f;
    }
    __syncthreads();
  }

  if (tid == 0) {
    float s = 0.0f;
    for (int k = 0; k < K; ++k) s += vals[k];
    s_inv = 1.0f / (s + 1e-8f);
  }
  __syncthreads();

  float* ob = out + (size_t)b * (NF + 2 * NR + NT);
  if (sl == 0) {
    for (int i = tid; i < NF; i += 256) ob[i] = 0.0f;
  } else if (sl == 1) {
    for (int i = tid; i < NR; i += 256) { ob[NF + i] = 0.0f; ob[NF + NR + i] = 0.0f; }
  } else {
    for (int i = tid; i < NT; i += 256) ob[NF + 2 * NR + i] = 0.0f;
  }
  __syncthreads();
  if (tid < K) {
    float v = vals[tid] * s_inv;
    int ix = idxs[tid];
    if (sl == 0) {
      ob[ix] = v;
    } else if (sl == 1) {
      ob[NF + ix] = v;
      ob[NF + NR + ix] = v;
    } else {
      ob[NF + 2 * NR + ix] = v;
    }
  }
}

// ---------------------------------------------------------------------------
extern "C" void kernel_launch(void* const* d_in, const int* in_sizes, int n_in,
                              void* d_out, int out_size, void* d_ws, size_t ws_size,
                              hipStream_t stream) {
  const float* x    = (const float*)d_in[0];   // [B,S,D]
  const float* imp  = (const float*)d_in[1];   // [B,S]
  const float* W    = (const float*)d_in[2];   // [D,DS]
  const float* bias = (const float*)d_in[3];   // [DS]
  const float* emb  = (const float*)d_in[4];   // [NTOT,DS]
  float* out = (float*)d_out;

  // workspace layout
  unsigned short* eh  = (unsigned short*)d_ws;            // NTOT*64
  unsigned short* el  = eh  + (size_t)NTOT * DS;
  unsigned short* wth = el  + (size_t)NTOT * DS;          // 64*2048
  unsigned short* wtl = wth + (size_t)DS * DIM;
  unsigned short* hh  = wtl + (size_t)DS * DIM;           // TOK*64
  unsigned short* hl  = hh  + (size_t)TOK * DS;
  float* Zp     = (float*)(hl + (size_t)TOK * DS);        // TOK*16
  float* a      = Zp + (size_t)TOK * 16;                  // 3*TOK
  float* Bp     = a + 3 * (size_t)TOK;                    // 128*NTOT
  float* pooled = Bp + (size_t)128 * NTOT;                // 4*NTOT
  float* Hpart  = pooled + (size_t)BATCH * NTOT;          // KSPLIT*TOK*64

  size_t need = (2 * (size_t)NTOT * DS + 2 * (size_t)DS * DIM +
                 2 * (size_t)TOK * DS) * sizeof(unsigned short) +
                ((size_t)TOK * 16 + 3 * (size_t)TOK + 128 * (size_t)NTOT +
                 (size_t)BATCH * NTOT + (size_t)KSPLIT * TOK * DS) * sizeof(float);
  if (ws_size < need) return;   // ~45 MB (R2 proved ws >= 281 MB)

  k_prep_emb<<<NTOT / 4, 256, 0, stream>>>(emb, eh, el);
  k_prep_w<<<DS, 256, 0, stream>>>(W, wth, wtl);
  k_h<<<dim3(TOK / 128, KSPLIT), 512, 0, stream>>>(x, wth, wtl, Hpart);
  k_hc<<<TOK * 16 / 256, 256, 0, stream>>>(Hpart, bias, hh, hl);

  k_zle<0><<<dim3(128, 16), 256, 0, stream>>>(hh, hl, eh, el, nullptr, Zp, nullptr);
  k_a2<<<TOK / 256, 256, 0, stream>>>(Zp, imp, a);
  k_zle<2><<<dim3(128, 16), 256, 0, stream>>>(hh, hl, eh, el, a, nullptr, Bp);
  k_red<<<(BATCH * NTOT) / 256, 256, 0, stream>>>(Bp, pooled);
  k_topk<<<12, 256, 0, stream>>>(pooled, out);
}